// Round 16
// baseline (799.251 us; speedup 1.0000x reference)
//
#include <hip/hip_runtime.h>
#include <hip/hip_bf16.h>

#define BB 128
#define SS 1024
#define HH 128
#define G3 384
#define NT (BB * SS)   // 131072 tokens

typedef __hip_bfloat16 bf16;
typedef unsigned int uint;
typedef unsigned short ushort;
typedef _Float16 f16;
typedef f16 f16x2 __attribute__((ext_vector_type(2)));
typedef f16 f16x8 __attribute__((ext_vector_type(8)));
typedef float f32x4 __attribute__((ext_vector_type(4)));

__device__ __forceinline__ float leaky(float x) { return x >= 0.f ? x : 0.01f * x; }
__device__ __forceinline__ f16x2 u2h(uint u) { return __builtin_bit_cast(f16x2, u); }
__device__ __forceinline__ uint packh2(float a, float b) {
  f16x2 h; h.x = (f16)a; h.y = (f16)b;
  return __builtin_bit_cast(uint, h);
}
__device__ __forceinline__ uint h1(float a) {
  return (uint)__builtin_bit_cast(ushort, (f16)a);
}
__device__ __forceinline__ uint bf_rne(float f) {
  uint u = __float_as_uint(f);
  return (u + 0x7FFFu + ((u >> 16) & 1u)) >> 16;
}
__device__ __forceinline__ float shflx(float v, int m) { return __shfl_xor(v, m, 64); }
__device__ __forceinline__ uint dpp_xor1_u(uint v) {
  int i = __builtin_amdgcn_update_dpp(0, (int)v, 0xB1, 0xF, 0xF, true);
  return (uint)i;
}
#define WSYNC() asm volatile("s_waitcnt lgkmcnt(0)" ::: "memory")

template <int NP>
__device__ __forceinline__ void ldrow(const float* __restrict__ p, f16x2* w) {
#pragma unroll
  for (int i = 0; i < NP; ++i) {
    f16x2 h; h.x = (f16)p[2 * i]; h.y = (f16)p[2 * i + 1];
    w[i] = h;
  }
}
__device__ __forceinline__ f16x8 ldw8(const float* __restrict__ p) {
  f16x8 v;
#pragma unroll
  for (int j = 0; j < 8; ++j) v[j] = (f16)p[j];
  return v;
}
template <int NP>
__device__ __forceinline__ float dot2l(const uint* __restrict__ x,
                                       const f16x2* __restrict__ w, float acc) {
#pragma unroll
  for (int i = 0; i < NP / 4; ++i) {
    uint4 uu = ((const uint4*)x)[i];
    acc = __builtin_amdgcn_fdot2(u2h(uu.x), w[4 * i + 0], acc, false);
    acc = __builtin_amdgcn_fdot2(u2h(uu.y), w[4 * i + 1], acc, false);
    acc = __builtin_amdgcn_fdot2(u2h(uu.z), w[4 * i + 2], acc, false);
    acc = __builtin_amdgcn_fdot2(u2h(uu.w), w[4 * i + 3], acc, false);
  }
  return acc;
}
__device__ __forceinline__ float d4(uint4 x, uint4 w, float acc) {
  acc = __builtin_amdgcn_fdot2(u2h(x.x), u2h(w.x), acc, false);
  acc = __builtin_amdgcn_fdot2(u2h(x.y), u2h(w.y), acc, false);
  acc = __builtin_amdgcn_fdot2(u2h(x.z), u2h(w.z), acc, false);
  acc = __builtin_amdgcn_fdot2(u2h(x.w), u2h(w.w), acc, false);
  return acc;
}

// ---------------- pre_a: encoders + attention + LN -> xnh (f16 pairs) -------
__global__ __launch_bounds__(256, 4) void pre_a(
    const float* __restrict__ obs, const float* __restrict__ me_w1,
    const float* __restrict__ me_b1, const float* __restrict__ me_w2,
    const float* __restrict__ me_b2, const float* __restrict__ ae_w1,
    const float* __restrict__ ae_b1, const float* __restrict__ ae_w2,
    const float* __restrict__ ae_b2, const float* __restrict__ ipw,
    const float* __restrict__ ipb, const float* __restrict__ opw,
    const float* __restrict__ opb, const float* __restrict__ lng,
    const float* __restrict__ lnb, uint* __restrict__ xnh) {
  __shared__ float ss[352];
  __shared__ __align__(16) uint4 w4[8 * 256];  // 32 KB: [chunk c][row r]
  __shared__ __align__(16) uint ex[4][176];

  const int tid = threadIdx.x;
  const int wid = tid >> 6, l = tid & 63;
  if (tid < 96) ss[tid] = me_w1[tid];
  if (tid < 32) ss[96 + tid] = me_b1[tid];
  if (tid < 192) ss[128 + tid] = ae_w1[tid];
  if (tid < 32) ss[320 + tid] = ae_b1[tid];

  for (int idx = tid; idx < 2048; idx += 256) {
    const int r = idx & 255, c = idx >> 8;
    const float* src =
        (r < 192 ? ipw + (size_t)r * 64 : opw + (size_t)(r - 192) * 64) + c * 8;
    uint4 u;
    u.x = packh2(src[0], src[1]);
    u.y = packh2(src[2], src[3]);
    u.z = packh2(src[4], src[5]);
    u.w = packh2(src[6], src[7]);
    w4[(c << 8) + r] = u;
  }

  f16x2 wme2[16], wae2[16];
  ldrow<16>(me_w2 + l * 32, wme2);
  ldrow<16>(ae_w2 + l * 32, wae2);
  const float bme2 = me_b2[l], bae2 = ae_b2[l];
  const float bq = ipb[l], bk = ipb[64 + l], bv = ipb[128 + l], bop = opb[l];
  const float gl = lng[l], bl = lnb[l];
  __syncthreads();

  uint* um = ex[wid];
  uint* ua = um + 32;
  uint* e1 = um + 48;
  uint* e2 = um + 80;
  uint* ea = um + 112;
  uint* ec = um + 144;

  for (int base = blockIdx.x * 4; base < NT; base += 4096) {
    const size_t token = base + wid;
    const float4* ob4 = (const float4*)(obs + token * 12);
    float4 o0 = ob4[0], o1 = ob4[1], o2 = ob4[2];

    const int row = l & 31;
    const bool m2h = l >= 32;
    float i0 = m2h ? o0.w : o0.x, i1 = m2h ? o1.x : o0.y, i2 = m2h ? o1.y : o0.z;
    float t1 = ss[96 + row] + i0 * ss[row * 3] + i1 * ss[row * 3 + 1] + i2 * ss[row * 3 + 2];
    t1 = leaky(t1);
    float ta = ss[320 + row] + o1.z * ss[128 + row * 6] + o1.w * ss[128 + row * 6 + 1] +
               o2.x * ss[128 + row * 6 + 2] + o2.y * ss[128 + row * 6 + 3] +
               o2.z * ss[128 + row * 6 + 4] + o2.w * ss[128 + row * 6 + 5];
    ta = leaky(ta);
    float t1p = shflx(t1, 1), tap = shflx(ta, 1);
    if (!(l & 1)) {
      um[l >> 1] = packh2(t1, t1p);
      if (l < 32) ua[l >> 1] = packh2(ta, tap);
    }
    WSYNC();

    float m1e = dot2l<16>(um, wme2, bme2);
    float m2e = dot2l<16>(um + 16, wme2, bme2);
    float ace = dot2l<16>(ua, wae2, bae2);
    float m1p = shflx(m1e, 1), m2p = shflx(m2e, 1), acp = shflx(ace, 1);
    if (!(l & 1)) {
      e1[l >> 1] = packh2(m1e, m1p);
      e2[l >> 1] = packh2(m2e, m2p);
      ea[l >> 1] = packh2(ace, acp);
    }
    WSYNC();

    float q = bq, k1 = bk, k2 = bk, v1 = bv, v2 = bv;
    {
      const uint4* xe1 = (const uint4*)e1;
      const uint4* xe2 = (const uint4*)e2;
      const uint4* xea = (const uint4*)ea;
#pragma unroll
      for (int c = 0; c < 8; ++c) {
        uint4 x1 = xe1[c], x2 = xe2[c], xa = xea[c];
        uint4 uq = w4[(c << 8) + l];
        uint4 uk = w4[(c << 8) + 64 + l];
        uint4 uv = w4[(c << 8) + 128 + l];
        q = d4(xa, uq, q);
        k1 = d4(x1, uk, k1);
        k2 = d4(x2, uk, k2);
        v1 = d4(x1, uv, v1);
        v2 = d4(x2, uv, v2);
      }
    }

    float p1 = q * k1, p2 = q * k2;
    p1 += shflx(p1, 1); p2 += shflx(p2, 1);
    p1 += shflx(p1, 2); p2 += shflx(p2, 2);
    p1 += shflx(p1, 4); p2 += shflx(p2, 4);
    p1 += shflx(p1, 8); p2 += shflx(p2, 8);
    float s1 = p1 * 0.25f, s2 = p2 * 0.25f;
    float mx = fmaxf(s1, s2);
    float ev1 = __expf(s1 - mx), ev2 = __expf(s2 - mx);
    float a1 = ev1 / (ev1 + ev2);
    float ctx = a1 * v1 + (1.f - a1) * v2;
    float cxp = shflx(ctx, 1);
    if (!(l & 1)) ec[l >> 1] = packh2(ctx, cxp);
    WSYNC();

    float ao = bop;
    {
      const uint4* xec = (const uint4*)ec;
#pragma unroll
      for (int c = 0; c < 8; ++c) {
        ao = d4(xec[c], w4[(c << 8) + 192 + l], ao);
      }
    }
    float x = ao + ace;
    float s = x, s2s = x * x;
#pragma unroll
    for (int off = 32; off; off >>= 1) {
      s += shflx(s, off);
      s2s += shflx(s2s, off);
    }
    float mu = s * (1.f / 64.f);
    float var = s2s * (1.f / 64.f) - mu * mu;
    float rs = rsqrtf(var + 1e-5f);
    float xn = (x - mu) * rs * gl + bl;
    float xnp = shflx(xn, 1);
    if (!(l & 1)) xnh[token * 32 + (l >> 1)] = packh2(xn, xnp);
  }
}

// ---------------- pre_b (MFMA): xp[NT,384] = xn[NT,64] @ W_ih^T + b ---------
__global__ __launch_bounds__(256) void pre_b(const uint* __restrict__ xnh,
                                             const float* __restrict__ wih,
                                             const float* __restrict__ bih,
                                             uint* __restrict__ xp32) {
  const int tid = threadIdx.x;
  const int l = tid & 63, wv = tid >> 6;
  const int n16 = l & 15, q = l >> 4;

  f16x8 Bf[6][2];
  float bias_l[6];
#pragma unroll
  for (int i = 0; i < 6; ++i) {
    const int n = (wv * 6 + i) * 16 + n16;
    const float* wrow = wih + (size_t)n * 64;
    Bf[i][0] = ldw8(wrow + q * 8);
    Bf[i][1] = ldw8(wrow + 32 + q * 8);
    bias_l[i] = bih[n];
  }

  for (int tile = blockIdx.x; tile < NT / 16; tile += gridDim.x) {
    const uint4* arow = (const uint4*)(xnh + (size_t)(tile * 16 + n16) * 32);
    f16x8 A0 = __builtin_bit_cast(f16x8, arow[q]);
    f16x8 A1 = __builtin_bit_cast(f16x8, arow[4 + q]);
#pragma unroll
    for (int i = 0; i < 6; ++i) {
      const int nt = wv * 6 + i;
      f32x4 acc = {0.f, 0.f, 0.f, 0.f};
      acc = __builtin_amdgcn_mfma_f32_16x16x32_f16(A0, Bf[i][0], acc, 0, 0, 0);
      acc = __builtin_amdgcn_mfma_f32_16x16x32_f16(A1, Bf[i][1], acc, 0, 0, 0);
#pragma unroll
      for (int r = 0; r < 4; ++r) {
        uint bv = bf_rne(acc[r] + bias_l[i]);
        uint pv = dpp_xor1_u(bv);
        if (!(l & 1))
          xp32[(size_t)(tile * 16 + q * 4 + r) * 192 + nt * 8 + (n16 >> 1)] =
              bv | (pv << 16);
      }
    }
  }
}

// ---------------- gru (MFMA matvec) + fused MLP head ------------------------
// r14 structure (4 compute waves + 1 producer, 1 lgkm barrier/step). Every 16
// steps the just-produced h-tile (hstage[16][128], rows=tokens, 16 uint4/row)
// runs the MLP head in-block: mlp0 (8 MFMA/wave) -> f0stage (C-layout scatter)
// -> mlp1 (8 MFMA/wave) -> ow-reduce -> value[16] store. Eliminates gout/f0h
// global round-trips and the mlp0/mlp1 kernels.
__global__ __launch_bounds__(320, 1) void gru_kernel(
    const bf16* __restrict__ xp, const float* __restrict__ hs,
    const float* __restrict__ whh, const float* __restrict__ bhh,
    const float* __restrict__ w0, const float* __restrict__ b0,
    const float* __restrict__ w1, const float* __restrict__ b1,
    const float* __restrict__ ow, const float* __restrict__ obp,
    float* __restrict__ value, float* __restrict__ hlast) {
  __shared__ __align__(16) ushort hbuf[2][HH];
  __shared__ __align__(16) uint ring[8 * 192];
  __shared__ __align__(16) ushort hstage[16][HH];   // row = token; 16 uint4/row
  __shared__ __align__(16) ushort f0stage[16][HH];
  __shared__ float vpart[64];
  const int tid = threadIdx.x;
  const int b = blockIdx.x;
  const bool comp = tid < 256;
  const int lane = tid & 63;
  const int w = tid >> 6;          // 0..3 compute, 4 producer
  const int n16 = lane & 15, q = lane >> 4;
  const int pid = tid - 256;

  f16x8 Bf[6][4];                  // W_hh fragments
  f16x8 Bm0[2][4], Bm1[2][4];      // mlp w0 / w1 fragments (n-tiles 2w,2w+1)
  float bias_r = 0.f, bias_z = 0.f, bias_g = 0.f, hp = 0.f;
  float mb0[2] = {0.f, 0.f}, mb1[2] = {0.f, 0.f}, owl[2] = {0.f, 0.f};
  int idx = 0;
  const float obias = obp[0];
  const uint* xr32 = (const uint*)(xp + (size_t)b * SS * G3);
  uint a0 = 0, a1 = 0, a2 = 0, c0 = 0, c1 = 0, c2 = 0;
  if (comp) {
    const int tn[6] = {2 * w, 2 * w + 1, 8 + 2 * w, 9 + 2 * w, 16 + 2 * w, 17 + 2 * w};
#pragma unroll
    for (int i = 0; i < 6; ++i) {
      const float* wrow = whh + (size_t)(tn[i] * 16 + n16) * HH;
#pragma unroll
      for (int kt = 0; kt < 4; ++kt) Bf[i][kt] = ldw8(wrow + kt * 32 + q * 8);
    }
#pragma unroll
    for (int i = 0; i < 2; ++i) {
      const int n = (2 * w + i) * 16 + n16;
#pragma unroll
      for (int f = 0; f < 4; ++f) {
        Bm0[i][f] = ldw8(w0 + (size_t)n * HH + f * 32 + q * 8);
        Bm1[i][f] = ldw8(w1 + (size_t)n * HH + f * 32 + q * 8);
      }
      mb0[i] = b0[n];
      mb1[i] = b1[n];
      owl[i] = ow[n];
    }
    idx = 32 * w + n16 + ((q >> 1) ? 16 : 0);
    bias_r = bhh[idx];
    bias_z = bhh[HH + idx];
    bias_g = bhh[2 * HH + idx];
    hp = hs[b * HH + idx];
    if (tid < HH) hbuf[0][tid] = (ushort)h1(hs[b * HH + tid]);
  } else {
    for (int s = 0; s < 4; ++s) {
      const uint* p = xr32 + s * 192 + pid * 3;
      uint v0 = p[0], v1 = p[1], v2 = p[2];
      uint* qq = ring + s * 192 + pid * 3;
      qq[0] = v0; qq[1] = v1; qq[2] = v2;
    }
    const uint* pa = xr32 + 4 * 192 + pid * 3;
    a0 = pa[0]; a1 = pa[1]; a2 = pa[2];
    const uint* pb = xr32 + 5 * 192 + pid * 3;
    c0 = pb[0]; c1 = pb[1]; c2 = pb[2];
  }
  __syncthreads();

  const ushort* ring_us = (const ushort*)ring;
  const bool pub = comp && !(q & 1);  // quads 0 and 2
  const int sel = q >> 1;

#define CSTEP(TT, RD, WRI)                                                     \
  {                                                                            \
    const int slot = (TT) & 7;                                                 \
    const uint4* hb = (const uint4*)hbuf[RD];                                  \
    f16x8 A0 = __builtin_bit_cast(f16x8, hb[q]);                               \
    f16x8 A1 = __builtin_bit_cast(f16x8, hb[4 + q]);                           \
    f16x8 A2 = __builtin_bit_cast(f16x8, hb[8 + q]);                           \
    f16x8 A3 = __builtin_bit_cast(f16x8, hb[12 + q]);                          \
    f32x4 ac0 = {0.f, 0.f, 0.f, 0.f}, ac1 = ac0, ac2 = ac0, ac3 = ac0,         \
          ac4 = ac0, ac5 = ac0;                                                \
    ac0 = __builtin_amdgcn_mfma_f32_16x16x32_f16(A0, Bf[0][0], ac0, 0, 0, 0);  \
    ac1 = __builtin_amdgcn_mfma_f32_16x16x32_f16(A0, Bf[1][0], ac1, 0, 0, 0);  \
    ac2 = __builtin_amdgcn_mfma_f32_16x16x32_f16(A0, Bf[2][0], ac2, 0, 0, 0);  \
    ac3 = __builtin_amdgcn_mfma_f32_16x16x32_f16(A0, Bf[3][0], ac3, 0, 0, 0);  \
    ac4 = __builtin_amdgcn_mfma_f32_16x16x32_f16(A0, Bf[4][0], ac4, 0, 0, 0);  \
    ac5 = __builtin_amdgcn_mfma_f32_16x16x32_f16(A0, Bf[5][0], ac5, 0, 0, 0);  \
    ac0 = __builtin_amdgcn_mfma_f32_16x16x32_f16(A1, Bf[0][1], ac0, 0, 0, 0);  \
    ac1 = __builtin_amdgcn_mfma_f32_16x16x32_f16(A1, Bf[1][1], ac1, 0, 0, 0);  \
    ac2 = __builtin_amdgcn_mfma_f32_16x16x32_f16(A1, Bf[2][1], ac2, 0, 0, 0);  \
    ac3 = __builtin_amdgcn_mfma_f32_16x16x32_f16(A1, Bf[3][1], ac3, 0, 0, 0);  \
    ac4 = __builtin_amdgcn_mfma_f32_16x16x32_f16(A1, Bf[4][1], ac4, 0, 0, 0);  \
    ac5 = __builtin_amdgcn_mfma_f32_16x16x32_f16(A1, Bf[5][1], ac5, 0, 0, 0);  \
    ac0 = __builtin_amdgcn_mfma_f32_16x16x32_f16(A2, Bf[0][2], ac0, 0, 0, 0);  \
    ac1 = __builtin_amdgcn_mfma_f32_16x16x32_f16(A2, Bf[1][2], ac1, 0, 0, 0);  \
    ac2 = __builtin_amdgcn_mfma_f32_16x16x32_f16(A2, Bf[2][2], ac2, 0, 0, 0);  \
    ac3 = __builtin_amdgcn_mfma_f32_16x16x32_f16(A2, Bf[3][2], ac3, 0, 0, 0);  \
    ac4 = __builtin_amdgcn_mfma_f32_16x16x32_f16(A2, Bf[4][2], ac4, 0, 0, 0);  \
    ac5 = __builtin_amdgcn_mfma_f32_16x16x32_f16(A2, Bf[5][2], ac5, 0, 0, 0);  \
    ac0 = __builtin_amdgcn_mfma_f32_16x16x32_f16(A3, Bf[0][3], ac0, 0, 0, 0);  \
    ac1 = __builtin_amdgcn_mfma_f32_16x16x32_f16(A3, Bf[1][3], ac1, 0, 0, 0);  \
    ac2 = __builtin_amdgcn_mfma_f32_16x16x32_f16(A3, Bf[2][3], ac2, 0, 0, 0);  \
    ac3 = __builtin_amdgcn_mfma_f32_16x16x32_f16(A3, Bf[3][3], ac3, 0, 0, 0);  \
    ac4 = __builtin_amdgcn_mfma_f32_16x16x32_f16(A3, Bf[4][3], ac4, 0, 0, 0);  \
    ac5 = __builtin_amdgcn_mfma_f32_16x16x32_f16(A3, Bf[5][3], ac5, 0, 0, 0);  \
    float Pr = (sel ? ac1[0] : ac0[0]) + bias_r;                               \
    float Pz = (sel ? ac3[0] : ac2[0]) + bias_z;                               \
    float Pg = (sel ? ac5[0] : ac4[0]) + bias_g;                               \
    uint bxr = ring_us[slot * 384 + idx];                                      \
    uint bxz = ring_us[slot * 384 + 128 + idx];                                \
    uint bxg = ring_us[slot * 384 + 256 + idx];                                \
    float r = 1.f / (1.f + __expf(-(__uint_as_float(bxr << 16) + Pr)));        \
    float z = 1.f / (1.f + __expf(-(__uint_as_float(bxz << 16) + Pz)));        \
    float gp = __uint_as_float(bxg << 16) + r * Pg;                            \
    float th = 2.f / (1.f + __expf(-2.f * gp)) - 1.f;                          \
    float hn = (1.f - z) * th + z * hp;                                        \
    hp = hn;                                                                   \
    if (pub) {                                                                 \
      ushort hb16 = (ushort)h1(hn);                                            \
      hbuf[WRI][idx] = hb16;                                                   \
      hstage[(TT) & 15][idx] = hb16;                                           \
    }                                                                          \
  }

#define PSTEP(TT, R0, R1, R2)                                                  \
  {                                                                            \
    const int wrow = (TT) + 4;                                                 \
    if (wrow < SS) {                                                           \
      uint* qq = ring + (wrow & 7) * 192 + pid * 3;                            \
      qq[0] = R0; qq[1] = R1; qq[2] = R2;                                      \
      const int lrow = (TT) + 6;                                               \
      if (lrow < SS) {                                                         \
        const uint* p = xr32 + lrow * 192 + pid * 3;                           \
        R0 = p[0]; R1 = p[1]; R2 = p[2];                                       \
      }                                                                        \
    }                                                                          \
  }

  for (int t0 = 0; t0 < SS; t0 += 16) {
    for (int u = 0; u < 16; u += 2) {
      const int t = t0 + u;
      if (comp) {
        CSTEP(t, 0, 1);
      } else {
        PSTEP(t, a0, a1, a2);
      }
      asm volatile("s_waitcnt lgkmcnt(0)\n\ts_barrier" ::: "memory");
      if (comp) {
        CSTEP(t + 1, 1, 0);
      } else {
        PSTEP(t + 1, c0, c1, c2);
      }
      asm volatile("s_waitcnt lgkmcnt(0)\n\ts_barrier" ::: "memory");
    }
    // ---- fused MLP head on tokens t0..t0+15 (hstage complete) ----
    if (comp) {
      const uint4* hs4 = (const uint4*)hstage;  // row stride = 16 uint4
      f16x8 A[4];
#pragma unroll
      for (int f = 0; f < 4; ++f)
        A[f] = __builtin_bit_cast(f16x8, hs4[n16 * 16 + f * 4 + q]);
#pragma unroll
      for (int i = 0; i < 2; ++i) {
        f32x4 acc = {0.f, 0.f, 0.f, 0.f};
#pragma unroll
        for (int f = 0; f < 4; ++f)
          acc = __builtin_amdgcn_mfma_f32_16x16x32_f16(A[f], Bm0[i][f], acc, 0, 0, 0);
#pragma unroll
        for (int r = 0; r < 4; ++r)
          f0stage[q * 4 + r][(2 * w + i) * 16 + n16] =
              (ushort)h1(leaky(acc[r] + mb0[i]));
      }
    }
    asm volatile("s_waitcnt lgkmcnt(0)\n\ts_barrier" ::: "memory");
    if (comp) {
      const uint4* fs4 = (const uint4*)f0stage;  // row stride = 16 uint4
      f16x8 A[4];
#pragma unroll
      for (int f = 0; f < 4; ++f)
        A[f] = __builtin_bit_cast(f16x8, fs4[n16 * 16 + f * 4 + q]);
      float s0 = 0.f, s1 = 0.f, s2 = 0.f, s3 = 0.f;
#pragma unroll
      for (int i = 0; i < 2; ++i) {
        f32x4 acc = {0.f, 0.f, 0.f, 0.f};
#pragma unroll
        for (int f = 0; f < 4; ++f)
          acc = __builtin_amdgcn_mfma_f32_16x16x32_f16(A[f], Bm1[i][f], acc, 0, 0, 0);
        s0 += leaky(acc[0] + mb1[i]) * owl[i];
        s1 += leaky(acc[1] + mb1[i]) * owl[i];
        s2 += leaky(acc[2] + mb1[i]) * owl[i];
        s3 += leaky(acc[3] + mb1[i]) * owl[i];
      }
#pragma unroll
      for (int m = 1; m < 16; m <<= 1) {
        s0 += shflx(s0, m);
        s1 += shflx(s1, m);
        s2 += shflx(s2, m);
        s3 += shflx(s3, m);
      }
      if (n16 == 0) {
        vpart[w * 16 + q * 4 + 0] = s0;
        vpart[w * 16 + q * 4 + 1] = s1;
        vpart[w * 16 + q * 4 + 2] = s2;
        vpart[w * 16 + q * 4 + 3] = s3;
      }
    }
    asm volatile("s_waitcnt lgkmcnt(0)\n\ts_barrier" ::: "memory");
    if (tid < 16) {
      float v = vpart[tid] + vpart[16 + tid] + vpart[32 + tid] + vpart[48 + tid] + obias;
      value[(size_t)b * SS + t0 + tid] = v;
    }
  }
#undef CSTEP
#undef PSTEP
  if (pub) hlast[b * HH + idx] = hp;
}

__global__ void fill_sentinel(float* o, int n) {
  for (int i = blockIdx.x * blockDim.x + threadIdx.x; i < n; i += gridDim.x * blockDim.x)
    o[i] = 999.0f;
}

extern "C" void kernel_launch(void* const* d_in, const int* in_sizes, int n_in,
                              void* d_out, int out_size, void* d_ws, size_t ws_size,
                              hipStream_t stream) {
  const float* obs = (const float*)d_in[0];
  const float* hs = (const float*)d_in[1];
  const float* me_w1 = (const float*)d_in[2];
  const float* me_b1 = (const float*)d_in[3];
  const float* me_w2 = (const float*)d_in[4];
  const float* me_b2 = (const float*)d_in[5];
  const float* ae_w1 = (const float*)d_in[6];
  const float* ae_b1 = (const float*)d_in[7];
  const float* ae_w2 = (const float*)d_in[8];
  const float* ae_b2 = (const float*)d_in[9];
  const float* ipw = (const float*)d_in[10];
  const float* ipb = (const float*)d_in[11];
  const float* opw = (const float*)d_in[12];
  const float* opb = (const float*)d_in[13];
  const float* lng = (const float*)d_in[14];
  const float* lnb = (const float*)d_in[15];
  const float* wih = (const float*)d_in[16];
  const float* whh = (const float*)d_in[17];
  const float* bih = (const float*)d_in[18];
  const float* bhh = (const float*)d_in[19];
  const float* w0 = (const float*)d_in[20];
  const float* b0 = (const float*)d_in[21];
  const float* w1 = (const float*)d_in[22];
  const float* b1 = (const float*)d_in[23];
  const float* ow = (const float*)d_in[24];
  const float* ob = (const float*)d_in[25];

  const size_t regA_bytes = (size_t)NT * G3 * sizeof(bf16);
  const size_t regB_bytes = (size_t)NT * 64 * sizeof(uint);
  const size_t need = regA_bytes + regB_bytes;  // 134,217,728
  float* out = (float*)d_out;
  if (ws_size < need) {
    fill_sentinel<<<288, 256, 0, stream>>>(out, out_size);
    return;
  }

  char* ws = (char*)d_ws;
  bf16* xp = (bf16*)ws;
  uint* xnh = (uint*)(ws + regA_bytes);

  pre_a<<<1024, 256, 0, stream>>>(obs, me_w1, me_b1, me_w2, me_b2, ae_w1, ae_b1,
                                  ae_w2, ae_b2, ipw, ipb, opw, opb, lng, lnb, xnh);
  pre_b<<<1024, 256, 0, stream>>>(xnh, wih, bih, (uint*)xp);
  gru_kernel<<<BB, 320, 0, stream>>>(xp, hs, whh, bhh, w0, b0, w1, b1, ow, ob,
                                     out, out + NT);
}

// Round 17
// 788.239 us; speedup vs baseline: 1.0140x; 1.0140x over previous
//
#include <hip/hip_runtime.h>
#include <hip/hip_bf16.h>

#define BB 128
#define SS 1024
#define HH 128
#define HSP (HH + 8)   // padded stage row: 136 ushorts = 17 uint4 (kills 16-way bank conflicts)
#define G3 384
#define NT (BB * SS)   // 131072 tokens

typedef __hip_bfloat16 bf16;
typedef unsigned int uint;
typedef unsigned short ushort;
typedef _Float16 f16;
typedef f16 f16x2 __attribute__((ext_vector_type(2)));
typedef f16 f16x8 __attribute__((ext_vector_type(8)));
typedef float f32x4 __attribute__((ext_vector_type(4)));

__device__ __forceinline__ float leaky(float x) { return x >= 0.f ? x : 0.01f * x; }
__device__ __forceinline__ f16x2 u2h(uint u) { return __builtin_bit_cast(f16x2, u); }
__device__ __forceinline__ uint packh2(float a, float b) {
  f16x2 h; h.x = (f16)a; h.y = (f16)b;
  return __builtin_bit_cast(uint, h);
}
__device__ __forceinline__ uint h1(float a) {
  return (uint)__builtin_bit_cast(ushort, (f16)a);
}
__device__ __forceinline__ uint bf_rne(float f) {
  uint u = __float_as_uint(f);
  return (u + 0x7FFFu + ((u >> 16) & 1u)) >> 16;
}
__device__ __forceinline__ float shflx(float v, int m) { return __shfl_xor(v, m, 64); }
__device__ __forceinline__ uint dpp_xor1_u(uint v) {
  int i = __builtin_amdgcn_update_dpp(0, (int)v, 0xB1, 0xF, 0xF, true);
  return (uint)i;
}
#define WSYNC() asm volatile("s_waitcnt lgkmcnt(0)" ::: "memory")

template <int NP>
__device__ __forceinline__ void ldrow(const float* __restrict__ p, f16x2* w) {
#pragma unroll
  for (int i = 0; i < NP; ++i) {
    f16x2 h; h.x = (f16)p[2 * i]; h.y = (f16)p[2 * i + 1];
    w[i] = h;
  }
}
__device__ __forceinline__ f16x8 ldw8(const float* __restrict__ p) {
  f16x8 v;
#pragma unroll
  for (int j = 0; j < 8; ++j) v[j] = (f16)p[j];
  return v;
}
template <int NP>
__device__ __forceinline__ float dot2l(const uint* __restrict__ x,
                                       const f16x2* __restrict__ w, float acc) {
#pragma unroll
  for (int i = 0; i < NP / 4; ++i) {
    uint4 uu = ((const uint4*)x)[i];
    acc = __builtin_amdgcn_fdot2(u2h(uu.x), w[4 * i + 0], acc, false);
    acc = __builtin_amdgcn_fdot2(u2h(uu.y), w[4 * i + 1], acc, false);
    acc = __builtin_amdgcn_fdot2(u2h(uu.z), w[4 * i + 2], acc, false);
    acc = __builtin_amdgcn_fdot2(u2h(uu.w), w[4 * i + 3], acc, false);
  }
  return acc;
}
__device__ __forceinline__ float d4(uint4 x, uint4 w, float acc) {
  acc = __builtin_amdgcn_fdot2(u2h(x.x), u2h(w.x), acc, false);
  acc = __builtin_amdgcn_fdot2(u2h(x.y), u2h(w.y), acc, false);
  acc = __builtin_amdgcn_fdot2(u2h(x.z), u2h(w.z), acc, false);
  acc = __builtin_amdgcn_fdot2(u2h(x.w), u2h(w.w), acc, false);
  return acc;
}

// ---------------- pre_a: encoders + attention + LN -> xnh (f16 pairs) -------
__global__ __launch_bounds__(256, 4) void pre_a(
    const float* __restrict__ obs, const float* __restrict__ me_w1,
    const float* __restrict__ me_b1, const float* __restrict__ me_w2,
    const float* __restrict__ me_b2, const float* __restrict__ ae_w1,
    const float* __restrict__ ae_b1, const float* __restrict__ ae_w2,
    const float* __restrict__ ae_b2, const float* __restrict__ ipw,
    const float* __restrict__ ipb, const float* __restrict__ opw,
    const float* __restrict__ opb, const float* __restrict__ lng,
    const float* __restrict__ lnb, uint* __restrict__ xnh) {
  __shared__ float ss[352];
  __shared__ __align__(16) uint4 w4[8 * 256];  // 32 KB: [chunk c][row r]
  __shared__ __align__(16) uint ex[4][176];

  const int tid = threadIdx.x;
  const int wid = tid >> 6, l = tid & 63;
  if (tid < 96) ss[tid] = me_w1[tid];
  if (tid < 32) ss[96 + tid] = me_b1[tid];
  if (tid < 192) ss[128 + tid] = ae_w1[tid];
  if (tid < 32) ss[320 + tid] = ae_b1[tid];

  for (int idx = tid; idx < 2048; idx += 256) {
    const int r = idx & 255, c = idx >> 8;
    const float* src =
        (r < 192 ? ipw + (size_t)r * 64 : opw + (size_t)(r - 192) * 64) + c * 8;
    uint4 u;
    u.x = packh2(src[0], src[1]);
    u.y = packh2(src[2], src[3]);
    u.z = packh2(src[4], src[5]);
    u.w = packh2(src[6], src[7]);
    w4[(c << 8) + r] = u;
  }

  f16x2 wme2[16], wae2[16];
  ldrow<16>(me_w2 + l * 32, wme2);
  ldrow<16>(ae_w2 + l * 32, wae2);
  const float bme2 = me_b2[l], bae2 = ae_b2[l];
  const float bq = ipb[l], bk = ipb[64 + l], bv = ipb[128 + l], bop = opb[l];
  const float gl = lng[l], bl = lnb[l];
  __syncthreads();

  uint* um = ex[wid];
  uint* ua = um + 32;
  uint* e1 = um + 48;
  uint* e2 = um + 80;
  uint* ea = um + 112;
  uint* ec = um + 144;

  for (int base = blockIdx.x * 4; base < NT; base += 4096) {
    const size_t token = base + wid;
    const float4* ob4 = (const float4*)(obs + token * 12);
    float4 o0 = ob4[0], o1 = ob4[1], o2 = ob4[2];

    const int row = l & 31;
    const bool m2h = l >= 32;
    float i0 = m2h ? o0.w : o0.x, i1 = m2h ? o1.x : o0.y, i2 = m2h ? o1.y : o0.z;
    float t1 = ss[96 + row] + i0 * ss[row * 3] + i1 * ss[row * 3 + 1] + i2 * ss[row * 3 + 2];
    t1 = leaky(t1);
    float ta = ss[320 + row] + o1.z * ss[128 + row * 6] + o1.w * ss[128 + row * 6 + 1] +
               o2.x * ss[128 + row * 6 + 2] + o2.y * ss[128 + row * 6 + 3] +
               o2.z * ss[128 + row * 6 + 4] + o2.w * ss[128 + row * 6 + 5];
    ta = leaky(ta);
    float t1p = shflx(t1, 1), tap = shflx(ta, 1);
    if (!(l & 1)) {
      um[l >> 1] = packh2(t1, t1p);
      if (l < 32) ua[l >> 1] = packh2(ta, tap);
    }
    WSYNC();

    float m1e = dot2l<16>(um, wme2, bme2);
    float m2e = dot2l<16>(um + 16, wme2, bme2);
    float ace = dot2l<16>(ua, wae2, bae2);
    float m1p = shflx(m1e, 1), m2p = shflx(m2e, 1), acp = shflx(ace, 1);
    if (!(l & 1)) {
      e1[l >> 1] = packh2(m1e, m1p);
      e2[l >> 1] = packh2(m2e, m2p);
      ea[l >> 1] = packh2(ace, acp);
    }
    WSYNC();

    float q = bq, k1 = bk, k2 = bk, v1 = bv, v2 = bv;
    {
      const uint4* xe1 = (const uint4*)e1;
      const uint4* xe2 = (const uint4*)e2;
      const uint4* xea = (const uint4*)ea;
#pragma unroll
      for (int c = 0; c < 8; ++c) {
        uint4 x1 = xe1[c], x2 = xe2[c], xa = xea[c];
        uint4 uq = w4[(c << 8) + l];
        uint4 uk = w4[(c << 8) + 64 + l];
        uint4 uv = w4[(c << 8) + 128 + l];
        q = d4(xa, uq, q);
        k1 = d4(x1, uk, k1);
        k2 = d4(x2, uk, k2);
        v1 = d4(x1, uv, v1);
        v2 = d4(x2, uv, v2);
      }
    }

    float p1 = q * k1, p2 = q * k2;
    p1 += shflx(p1, 1); p2 += shflx(p2, 1);
    p1 += shflx(p1, 2); p2 += shflx(p2, 2);
    p1 += shflx(p1, 4); p2 += shflx(p2, 4);
    p1 += shflx(p1, 8); p2 += shflx(p2, 8);
    float s1 = p1 * 0.25f, s2 = p2 * 0.25f;
    float mx = fmaxf(s1, s2);
    float ev1 = __expf(s1 - mx), ev2 = __expf(s2 - mx);
    float a1 = ev1 / (ev1 + ev2);
    float ctx = a1 * v1 + (1.f - a1) * v2;
    float cxp = shflx(ctx, 1);
    if (!(l & 1)) ec[l >> 1] = packh2(ctx, cxp);
    WSYNC();

    float ao = bop;
    {
      const uint4* xec = (const uint4*)ec;
#pragma unroll
      for (int c = 0; c < 8; ++c) {
        ao = d4(xec[c], w4[(c << 8) + 192 + l], ao);
      }
    }
    float x = ao + ace;
    float s = x, s2s = x * x;
#pragma unroll
    for (int off = 32; off; off >>= 1) {
      s += shflx(s, off);
      s2s += shflx(s2s, off);
    }
    float mu = s * (1.f / 64.f);
    float var = s2s * (1.f / 64.f) - mu * mu;
    float rs = rsqrtf(var + 1e-5f);
    float xn = (x - mu) * rs * gl + bl;
    float xnp = shflx(xn, 1);
    if (!(l & 1)) xnh[token * 32 + (l >> 1)] = packh2(xn, xnp);
  }
}

// ---------------- pre_b (MFMA): xp[NT,384] = xn[NT,64] @ W_ih^T + b ---------
__global__ __launch_bounds__(256) void pre_b(const uint* __restrict__ xnh,
                                             const float* __restrict__ wih,
                                             const float* __restrict__ bih,
                                             uint* __restrict__ xp32) {
  const int tid = threadIdx.x;
  const int l = tid & 63, wv = tid >> 6;
  const int n16 = l & 15, q = l >> 4;

  f16x8 Bf[6][2];
  float bias_l[6];
#pragma unroll
  for (int i = 0; i < 6; ++i) {
    const int n = (wv * 6 + i) * 16 + n16;
    const float* wrow = wih + (size_t)n * 64;
    Bf[i][0] = ldw8(wrow + q * 8);
    Bf[i][1] = ldw8(wrow + 32 + q * 8);
    bias_l[i] = bih[n];
  }

  for (int tile = blockIdx.x; tile < NT / 16; tile += gridDim.x) {
    const uint4* arow = (const uint4*)(xnh + (size_t)(tile * 16 + n16) * 32);
    f16x8 A0 = __builtin_bit_cast(f16x8, arow[q]);
    f16x8 A1 = __builtin_bit_cast(f16x8, arow[4 + q]);
#pragma unroll
    for (int i = 0; i < 6; ++i) {
      const int nt = wv * 6 + i;
      f32x4 acc = {0.f, 0.f, 0.f, 0.f};
      acc = __builtin_amdgcn_mfma_f32_16x16x32_f16(A0, Bf[i][0], acc, 0, 0, 0);
      acc = __builtin_amdgcn_mfma_f32_16x16x32_f16(A1, Bf[i][1], acc, 0, 0, 0);
#pragma unroll
      for (int r = 0; r < 4; ++r) {
        uint bv = bf_rne(acc[r] + bias_l[i]);
        uint pv = dpp_xor1_u(bv);
        if (!(l & 1))
          xp32[(size_t)(tile * 16 + q * 4 + r) * 192 + nt * 8 + (n16 >> 1)] =
              bv | (pv << 16);
      }
    }
  }
}

// ---------------- gru (MFMA matvec) + fused MLP head (padded stages) --------
__global__ __launch_bounds__(320, 1) void gru_kernel(
    const bf16* __restrict__ xp, const float* __restrict__ hs,
    const float* __restrict__ whh, const float* __restrict__ bhh,
    const float* __restrict__ w0, const float* __restrict__ b0,
    const float* __restrict__ w1, const float* __restrict__ b1,
    const float* __restrict__ ow, const float* __restrict__ obp,
    float* __restrict__ value, float* __restrict__ hlast) {
  __shared__ __align__(16) ushort hbuf[2][HH];
  __shared__ __align__(16) uint ring[8 * 192];
  __shared__ __align__(16) ushort hstage[16][HSP];   // padded rows (17 uint4)
  __shared__ __align__(16) ushort f0stage[16][HSP];
  __shared__ float vpart[64];
  const int tid = threadIdx.x;
  const int b = blockIdx.x;
  const bool comp = tid < 256;
  const int lane = tid & 63;
  const int w = tid >> 6;          // 0..3 compute, 4 producer
  const int n16 = lane & 15, q = lane >> 4;
  const int pid = tid - 256;

  f16x8 Bf[6][4];                  // W_hh fragments
  f16x8 Bm0[2][4], Bm1[2][4];      // mlp w0 / w1 fragments (n-tiles 2w,2w+1)
  float bias_r = 0.f, bias_z = 0.f, bias_g = 0.f, hp = 0.f;
  float mb0[2] = {0.f, 0.f}, mb1[2] = {0.f, 0.f}, owl[2] = {0.f, 0.f};
  int idx = 0;
  const float obias = obp[0];
  const uint* xr32 = (const uint*)(xp + (size_t)b * SS * G3);
  uint a0 = 0, a1 = 0, a2 = 0, c0 = 0, c1 = 0, c2 = 0;
  if (comp) {
    const int tn[6] = {2 * w, 2 * w + 1, 8 + 2 * w, 9 + 2 * w, 16 + 2 * w, 17 + 2 * w};
#pragma unroll
    for (int i = 0; i < 6; ++i) {
      const float* wrow = whh + (size_t)(tn[i] * 16 + n16) * HH;
#pragma unroll
      for (int kt = 0; kt < 4; ++kt) Bf[i][kt] = ldw8(wrow + kt * 32 + q * 8);
    }
#pragma unroll
    for (int i = 0; i < 2; ++i) {
      const int n = (2 * w + i) * 16 + n16;
#pragma unroll
      for (int f = 0; f < 4; ++f) {
        Bm0[i][f] = ldw8(w0 + (size_t)n * HH + f * 32 + q * 8);
        Bm1[i][f] = ldw8(w1 + (size_t)n * HH + f * 32 + q * 8);
      }
      mb0[i] = b0[n];
      mb1[i] = b1[n];
      owl[i] = ow[n];
    }
    idx = 32 * w + n16 + ((q >> 1) ? 16 : 0);
    bias_r = bhh[idx];
    bias_z = bhh[HH + idx];
    bias_g = bhh[2 * HH + idx];
    hp = hs[b * HH + idx];
    if (tid < HH) hbuf[0][tid] = (ushort)h1(hs[b * HH + tid]);
  } else {
    for (int s = 0; s < 4; ++s) {
      const uint* p = xr32 + s * 192 + pid * 3;
      uint v0 = p[0], v1 = p[1], v2 = p[2];
      uint* qq = ring + s * 192 + pid * 3;
      qq[0] = v0; qq[1] = v1; qq[2] = v2;
    }
    const uint* pa = xr32 + 4 * 192 + pid * 3;
    a0 = pa[0]; a1 = pa[1]; a2 = pa[2];
    const uint* pb = xr32 + 5 * 192 + pid * 3;
    c0 = pb[0]; c1 = pb[1]; c2 = pb[2];
  }
  __syncthreads();

  const ushort* ring_us = (const ushort*)ring;
  const bool pub = comp && !(q & 1);  // quads 0 and 2
  const int sel = q >> 1;

#define CSTEP(TT, RD, WRI)                                                     \
  {                                                                            \
    const int slot = (TT) & 7;                                                 \
    const uint4* hb = (const uint4*)hbuf[RD];                                  \
    f16x8 A0 = __builtin_bit_cast(f16x8, hb[q]);                               \
    f16x8 A1 = __builtin_bit_cast(f16x8, hb[4 + q]);                           \
    f16x8 A2 = __builtin_bit_cast(f16x8, hb[8 + q]);                           \
    f16x8 A3 = __builtin_bit_cast(f16x8, hb[12 + q]);                          \
    f32x4 ac0 = {0.f, 0.f, 0.f, 0.f}, ac1 = ac0, ac2 = ac0, ac3 = ac0,         \
          ac4 = ac0, ac5 = ac0;                                                \
    ac0 = __builtin_amdgcn_mfma_f32_16x16x32_f16(A0, Bf[0][0], ac0, 0, 0, 0);  \
    ac1 = __builtin_amdgcn_mfma_f32_16x16x32_f16(A0, Bf[1][0], ac1, 0, 0, 0);  \
    ac2 = __builtin_amdgcn_mfma_f32_16x16x32_f16(A0, Bf[2][0], ac2, 0, 0, 0);  \
    ac3 = __builtin_amdgcn_mfma_f32_16x16x32_f16(A0, Bf[3][0], ac3, 0, 0, 0);  \
    ac4 = __builtin_amdgcn_mfma_f32_16x16x32_f16(A0, Bf[4][0], ac4, 0, 0, 0);  \
    ac5 = __builtin_amdgcn_mfma_f32_16x16x32_f16(A0, Bf[5][0], ac5, 0, 0, 0);  \
    ac0 = __builtin_amdgcn_mfma_f32_16x16x32_f16(A1, Bf[0][1], ac0, 0, 0, 0);  \
    ac1 = __builtin_amdgcn_mfma_f32_16x16x32_f16(A1, Bf[1][1], ac1, 0, 0, 0);  \
    ac2 = __builtin_amdgcn_mfma_f32_16x16x32_f16(A1, Bf[2][1], ac2, 0, 0, 0);  \
    ac3 = __builtin_amdgcn_mfma_f32_16x16x32_f16(A1, Bf[3][1], ac3, 0, 0, 0);  \
    ac4 = __builtin_amdgcn_mfma_f32_16x16x32_f16(A1, Bf[4][1], ac4, 0, 0, 0);  \
    ac5 = __builtin_amdgcn_mfma_f32_16x16x32_f16(A1, Bf[5][1], ac5, 0, 0, 0);  \
    ac0 = __builtin_amdgcn_mfma_f32_16x16x32_f16(A2, Bf[0][2], ac0, 0, 0, 0);  \
    ac1 = __builtin_amdgcn_mfma_f32_16x16x32_f16(A2, Bf[1][2], ac1, 0, 0, 0);  \
    ac2 = __builtin_amdgcn_mfma_f32_16x16x32_f16(A2, Bf[2][2], ac2, 0, 0, 0);  \
    ac3 = __builtin_amdgcn_mfma_f32_16x16x32_f16(A2, Bf[3][2], ac3, 0, 0, 0);  \
    ac4 = __builtin_amdgcn_mfma_f32_16x16x32_f16(A2, Bf[4][2], ac4, 0, 0, 0);  \
    ac5 = __builtin_amdgcn_mfma_f32_16x16x32_f16(A2, Bf[5][2], ac5, 0, 0, 0);  \
    ac0 = __builtin_amdgcn_mfma_f32_16x16x32_f16(A3, Bf[0][3], ac0, 0, 0, 0);  \
    ac1 = __builtin_amdgcn_mfma_f32_16x16x32_f16(A3, Bf[1][3], ac1, 0, 0, 0);  \
    ac2 = __builtin_amdgcn_mfma_f32_16x16x32_f16(A3, Bf[2][3], ac2, 0, 0, 0);  \
    ac3 = __builtin_amdgcn_mfma_f32_16x16x32_f16(A3, Bf[3][3], ac3, 0, 0, 0);  \
    ac4 = __builtin_amdgcn_mfma_f32_16x16x32_f16(A3, Bf[4][3], ac4, 0, 0, 0);  \
    ac5 = __builtin_amdgcn_mfma_f32_16x16x32_f16(A3, Bf[5][3], ac5, 0, 0, 0);  \
    float Pr = (sel ? ac1[0] : ac0[0]) + bias_r;                               \
    float Pz = (sel ? ac3[0] : ac2[0]) + bias_z;                               \
    float Pg = (sel ? ac5[0] : ac4[0]) + bias_g;                               \
    uint bxr = ring_us[slot * 384 + idx];                                      \
    uint bxz = ring_us[slot * 384 + 128 + idx];                                \
    uint bxg = ring_us[slot * 384 + 256 + idx];                                \
    float r = 1.f / (1.f + __expf(-(__uint_as_float(bxr << 16) + Pr)));        \
    float z = 1.f / (1.f + __expf(-(__uint_as_float(bxz << 16) + Pz)));        \
    float gp = __uint_as_float(bxg << 16) + r * Pg;                            \
    float th = 2.f / (1.f + __expf(-2.f * gp)) - 1.f;                          \
    float hn = (1.f - z) * th + z * hp;                                        \
    hp = hn;                                                                   \
    if (pub) {                                                                 \
      ushort hb16 = (ushort)h1(hn);                                            \
      hbuf[WRI][idx] = hb16;                                                   \
      hstage[(TT) & 15][idx] = hb16;                                           \
    }                                                                          \
  }

#define PSTEP(TT, R0, R1, R2)                                                  \
  {                                                                            \
    const int wrow = (TT) + 4;                                                 \
    if (wrow < SS) {                                                           \
      uint* qq = ring + (wrow & 7) * 192 + pid * 3;                            \
      qq[0] = R0; qq[1] = R1; qq[2] = R2;                                      \
      const int lrow = (TT) + 6;                                               \
      if (lrow < SS) {                                                         \
        const uint* p = xr32 + lrow * 192 + pid * 3;                           \
        R0 = p[0]; R1 = p[1]; R2 = p[2];                                       \
      }                                                                        \
    }                                                                          \
  }

  for (int t0 = 0; t0 < SS; t0 += 16) {
    for (int u = 0; u < 16; u += 2) {
      const int t = t0 + u;
      if (comp) {
        CSTEP(t, 0, 1);
      } else {
        PSTEP(t, a0, a1, a2);
      }
      asm volatile("s_waitcnt lgkmcnt(0)\n\ts_barrier" ::: "memory");
      if (comp) {
        CSTEP(t + 1, 1, 0);
      } else {
        PSTEP(t + 1, c0, c1, c2);
      }
      asm volatile("s_waitcnt lgkmcnt(0)\n\ts_barrier" ::: "memory");
    }
    // ---- fused MLP head on tokens t0..t0+15 (hstage complete) ----
    if (comp) {
      f16x8 A[4];
#pragma unroll
      for (int f = 0; f < 4; ++f)
        A[f] = __builtin_bit_cast(f16x8, ((const uint4*)hstage[n16])[f * 4 + q]);
#pragma unroll
      for (int i = 0; i < 2; ++i) {
        f32x4 acc = {0.f, 0.f, 0.f, 0.f};
#pragma unroll
        for (int f = 0; f < 4; ++f)
          acc = __builtin_amdgcn_mfma_f32_16x16x32_f16(A[f], Bm0[i][f], acc, 0, 0, 0);
#pragma unroll
        for (int r = 0; r < 4; ++r)
          f0stage[q * 4 + r][(2 * w + i) * 16 + n16] =
              (ushort)h1(leaky(acc[r] + mb0[i]));
      }
    }
    asm volatile("s_waitcnt lgkmcnt(0)\n\ts_barrier" ::: "memory");
    if (comp) {
      f16x8 A[4];
#pragma unroll
      for (int f = 0; f < 4; ++f)
        A[f] = __builtin_bit_cast(f16x8, ((const uint4*)f0stage[n16])[f * 4 + q]);
      float s0 = 0.f, s1 = 0.f, s2 = 0.f, s3 = 0.f;
#pragma unroll
      for (int i = 0; i < 2; ++i) {
        f32x4 acc = {0.f, 0.f, 0.f, 0.f};
#pragma unroll
        for (int f = 0; f < 4; ++f)
          acc = __builtin_amdgcn_mfma_f32_16x16x32_f16(A[f], Bm1[i][f], acc, 0, 0, 0);
        s0 += leaky(acc[0] + mb1[i]) * owl[i];
        s1 += leaky(acc[1] + mb1[i]) * owl[i];
        s2 += leaky(acc[2] + mb1[i]) * owl[i];
        s3 += leaky(acc[3] + mb1[i]) * owl[i];
      }
#pragma unroll
      for (int m = 1; m < 16; m <<= 1) {
        s0 += shflx(s0, m);
        s1 += shflx(s1, m);
        s2 += shflx(s2, m);
        s3 += shflx(s3, m);
      }
      if (n16 == 0) {
        vpart[w * 16 + q * 4 + 0] = s0;
        vpart[w * 16 + q * 4 + 1] = s1;
        vpart[w * 16 + q * 4 + 2] = s2;
        vpart[w * 16 + q * 4 + 3] = s3;
      }
    }
    asm volatile("s_waitcnt lgkmcnt(0)\n\ts_barrier" ::: "memory");
    if (tid < 16) {
      float v = vpart[tid] + vpart[16 + tid] + vpart[32 + tid] + vpart[48 + tid] + obias;
      value[(size_t)b * SS + t0 + tid] = v;
    }
  }
#undef CSTEP
#undef PSTEP
  if (pub) hlast[b * HH + idx] = hp;
}

__global__ void fill_sentinel(float* o, int n) {
  for (int i = blockIdx.x * blockDim.x + threadIdx.x; i < n; i += gridDim.x * blockDim.x)
    o[i] = 999.0f;
}

extern "C" void kernel_launch(void* const* d_in, const int* in_sizes, int n_in,
                              void* d_out, int out_size, void* d_ws, size_t ws_size,
                              hipStream_t stream) {
  const float* obs = (const float*)d_in[0];
  const float* hs = (const float*)d_in[1];
  const float* me_w1 = (const float*)d_in[2];
  const float* me_b1 = (const float*)d_in[3];
  const float* me_w2 = (const float*)d_in[4];
  const float* me_b2 = (const float*)d_in[5];
  const float* ae_w1 = (const float*)d_in[6];
  const float* ae_b1 = (const float*)d_in[7];
  const float* ae_w2 = (const float*)d_in[8];
  const float* ae_b2 = (const float*)d_in[9];
  const float* ipw = (const float*)d_in[10];
  const float* ipb = (const float*)d_in[11];
  const float* opw = (const float*)d_in[12];
  const float* opb = (const float*)d_in[13];
  const float* lng = (const float*)d_in[14];
  const float* lnb = (const float*)d_in[15];
  const float* wih = (const float*)d_in[16];
  const float* whh = (const float*)d_in[17];
  const float* bih = (const float*)d_in[18];
  const float* bhh = (const float*)d_in[19];
  const float* w0 = (const float*)d_in[20];
  const float* b0 = (const float*)d_in[21];
  const float* w1 = (const float*)d_in[22];
  const float* b1 = (const float*)d_in[23];
  const float* ow = (const float*)d_in[24];
  const float* ob = (const float*)d_in[25];

  const size_t regA_bytes = (size_t)NT * G3 * sizeof(bf16);
  const size_t regB_bytes = (size_t)NT * 64 * sizeof(uint);
  const size_t need = regA_bytes + regB_bytes;  // 134,217,728
  float* out = (float*)d_out;
  if (ws_size < need) {
    fill_sentinel<<<288, 256, 0, stream>>>(out, out_size);
    return;
  }

  char* ws = (char*)d_ws;
  bf16* xp = (bf16*)ws;
  uint* xnh = (uint*)(ws + regA_bytes);

  pre_a<<<1024, 256, 0, stream>>>(obs, me_w1, me_b1, me_w2, me_b2, ae_w1, ae_b1,
                                  ae_w2, ae_b2, ipw, ipb, opw, opb, lng, lnb, xnh);
  pre_b<<<1024, 256, 0, stream>>>(xnh, wih, bih, (uint*)xp);
  gru_kernel<<<BB, 320, 0, stream>>>(xp, hs, whh, bhh, w0, b0, w1, b1, ow, ob,
                                     out, out + NT);
}